// Round 11
// baseline (725.853 us; speedup 1.0000x reference)
//
#include <hip/hip_runtime.h>
#include <math.h>

// PointPWC multi-scale loss. B=2, scales N={8192,4096,2048,1024}.
// Inputs (B,3,N) fp32 channel-major: pc1_0..3, pc2_0..3, flow_0..3.
// Output: single fp32 scalar.
//
// R11: candidates moved OFF the LDS pipe. Cross-round counter fit showed
// the per-CU LDS pipe saturated by wave-uniform ds_read_b128 broadcasts
// (~16-20 cyc each, shared by 32 waves) -> real VALU util 39-55% in
// R5/R8/R10. Scan now reads candidates as uniform float4 loads from
// global (3 loads / 4 cands, __restrict__ -> scalarizable to s_load;
// even as VMEM a same-address load is one L1 line + broadcast).
// LDS tile kept only for pass D (needs p1+fl; 12% of work).

#define BLOCK 512
#define UNIT 1024    // candidates per wave-unit
#define NTOT 15360   // 8192+4096+2048+1024
#define MASKC 0xFFFFE000u
#define PB 340       // blocks per pass
#define STR 11       // merge-staging stride (odd -> 2-way alias only)

typedef unsigned int uint;

struct Params {
  const float* __restrict__ pc1[4];
  const float* __restrict__ pc2[4];
  const float* __restrict__ fl[4];
  float4* __restrict__ cv2;   // [B][NTOT]
  float4* __restrict__ cvw;   // [B][NTOT]
  float* __restrict__ ckeys;  // [B][NTOT][5] pass-C merged top-5 keys
  float* __restrict__ out;
};

// r in [0,340) -> scale s, batch b, 64-query-group base i0, cand lo.
__device__ __forceinline__ void decode(int r, int wv, int& s, int& b,
                                       int& i0, int& lo, int& N, int& cpw,
                                       int& off, float& alpha) {
  int rr;
  if (r < 256)      { s = 0; rr = r; }
  else if (r < 320) { s = 1; rr = r - 256; }
  else if (r < 336) { s = 2; rr = r - 320; }
  else              { s = 3; rr = r - 336; }
  N = 8192 >> s;
  cpw = 8 >> s;                       // candidate-ranges per qgroup
  int perb = 128 >> (2 * s);          // blocks per batch
  b = rr >> (7 - 2 * s);
  int chunk = rr & (perb - 1);
  int qg = (chunk << s) + (wv >> (3 - s));
  i0 = qg << 6;
  lo = (wv & (cpw - 1)) << 10;
  off = 16384 - (16384 >> s);         // {0, 8192, 12288, 14336}
  alpha = 0.02f * (float)(1 << s);
}

__device__ __forceinline__ float wave_sum(float v) {
  #pragma unroll
  for (int o = 32; o; o >>= 1) v += __shfl_down(v, o, 64);
  return v;
}

template <int K>
__device__ __forceinline__ void key_insert(float (&kd)[K], float kf) {
  #pragma unroll
  for (int m = K - 1; m >= 1; --m)
    kd[m] = __builtin_amdgcn_fmed3f(kf, kd[m - 1], kd[m]);
  kd[0] = fminf(kd[0], kf);
}

template <int K>
__device__ __forceinline__ void merge_pair(float (&a)[K], const float (&b)[K]) {
  #pragma unroll
  for (int m = 0; m < K; ++m) key_insert<K>(a, b[m]);
}

__device__ __forceinline__ float pack_key(float d, uint iw) {
  return __uint_as_float((__float_as_uint(d) & MASKC) | iw);
}

// Scan [lo, lo+UNIT): 1 query/thread, dual chains, candidates read as
// wave-uniform float4 global loads (no LDS). Arrays are 16B-aligned at
// float4 granularity (N multiples of 1024).
template <int K>
__device__ void scan_g(const float* __restrict__ px,
                       const float* __restrict__ py,
                       const float* __restrict__ pz,
                       int lo, float ax, float ay, float az,
                       float (&a)[K], float (&b)[K]) {
  const float4* __restrict__ px4 = (const float4*)(px + lo);
  const float4* __restrict__ py4 = (const float4*)(py + lo);
  const float4* __restrict__ pz4 = (const float4*)(pz + lo);
  #pragma unroll 4
  for (int g = 0; g < UNIT / 4; ++g) {
    float4 xs = px4[g], ys = py4[g], zs = pz4[g];
    uint c = (uint)(lo + g * 4);
    // cands c,c+1 -> chain a; c+2,c+3 -> chain b
    float dx0 = ax - xs.x, dy0 = ay - ys.x, dz0 = az - zs.x;
    float d0 = fmaf(dx0, dx0, fmaf(dy0, dy0, dz0 * dz0));
    float dx1 = ax - xs.y, dy1 = ay - ys.y, dz1 = az - zs.y;
    float d1 = fmaf(dx1, dx1, fmaf(dy1, dy1, dz1 * dz1));
    float dx2 = ax - xs.z, dy2 = ay - ys.z, dz2 = az - zs.z;
    float d2 = fmaf(dx2, dx2, fmaf(dy2, dy2, dz2 * dz2));
    float dx3 = ax - xs.w, dy3 = ay - ys.w, dz3 = az - zs.w;
    float d3 = fmaf(dx3, dx3, fmaf(dy3, dy3, dz3 * dz3));
    key_insert<K>(a, pack_key(d0, c));
    key_insert<K>(b, pack_key(d2, c + 2));
    key_insert<K>(a, pack_key(d1, c + 1));
    key_insert<K>(b, pack_key(d3, c + 3));
  }
}

// Pass D scan: candidates are p1+fl, staged through this wave's private
// AoS float4 LDS tile (aligned ds_read_b128 broadcast). Only ~12% of
// blocks use this path -> LDS pipe unsaturated.
__device__ void scan_min(const float* __restrict__ px,
                         const float* __restrict__ py,
                         const float* __restrict__ pz,
                         const float* __restrict__ fx,
                         const float* __restrict__ fy,
                         const float* __restrict__ fz,
                         int lo, float ax, float ay, float az,
                         float& a, float& b, float4* tile, int lane) {
  int j = lo + lane;
  float x = px[j] + fx[j], y = py[j] + fy[j], z = pz[j] + fz[j];
  for (int c0 = lo; c0 < lo + UNIT; c0 += 64) {
    tile[lane] = make_float4(x, y, z, 0.f);
    asm volatile("s_waitcnt lgkmcnt(0)" ::: "memory");
    if (c0 + 64 < lo + UNIT) {
      int jn = j + 64;
      x = px[jn] + fx[jn]; y = py[jn] + fy[jn]; z = pz[jn] + fz[jn];
    }
    #pragma unroll 8
    for (int t = 0; t < 64; t += 2) {
      float4 cA = tile[t];
      float4 cB = tile[t + 1];
      float dxa = ax - cA.x, dya = ay - cA.y, dza = az - cA.z;
      float dA = fmaf(dxa, dxa, fmaf(dya, dya, dza * dza));
      float dxb = ax - cB.x, dyb = ay - cB.y, dzb = az - cB.z;
      float dB = fmaf(dxb, dxb, fmaf(dyb, dyb, dzb * dzb));
      a = fminf(a, dA);
      b = fminf(b, dB);
    }
    j += 64;
  }
}

// Stage per-thread list; group leader (wave with range 0) merges its
// qgroup's cpw lists. Returns true for leader threads.
template <int K>
__device__ __forceinline__ bool merge_group(float (&a)[K], float* sm,
                                            int tid, int cpw) {
  int q = tid & 63, wv = tid >> 6;
  #pragma unroll
  for (int m = 0; m < K; ++m) sm[(wv * 64 + q) * STR + m] = a[m];
  __syncthreads();
  if (wv & (cpw - 1)) return false;
  for (int w = wv + 1; w < wv + cpw; ++w)
    #pragma unroll
    for (int m = 0; m < K; ++m)
      key_insert<K>(a, sm[(w * 64 + q) * STR + m]);
  return true;
}

__global__ __launch_bounds__(1) void k_zero(float* out) { out[0] = 0.f; }

// pass 0 (A): self-KNN p2 k=10 -> cv2
// pass 1 (B): self-KNN p1 k=10 -> cvw + smoothness
// pass 2 (C): warp->p2 top-5 scan -> merged keys to ws (epilogue: k_tail)
// pass 3 (D): p2 -> warp min (dist2)
__global__ __launch_bounds__(BLOCK, 8) void k_fused(Params P) {
  __shared__ float4 tiles[8][64];        // 8 KB (pass D only)
  __shared__ float sm[8 * 64 * STR];     // 22.5 KB
  int tid = threadIdx.x, q = tid & 63, wv = tid >> 6;
  int pass = blockIdx.x & 3, r = blockIdx.x >> 2;
  int s, b, i0, lo, N, cpw, off; float alpha;
  decode(r, wv, s, b, i0, lo, N, cpw, off, alpha);
  int i = i0 + q;

  const float* __restrict__ p1 = P.pc1[s] + b * 3 * N;
  const float* __restrict__ fl = P.fl[s] + b * 3 * N;
  const float* __restrict__ p2 = P.pc2[s] + b * 3 * N;

  if (pass == 0) {
    float ax = p2[i], ay = p2[N + i], az = p2[2 * N + i];
    float a[10], bb[10];
    #pragma unroll
    for (int m = 0; m < 10; ++m) { a[m] = 3.0e38f; bb[m] = 3.0e38f; }
    scan_g<10>(p2, p2 + N, p2 + 2 * N, lo, ax, ay, az, a, bb);
    merge_pair<10>(a, bb);
    if (!merge_group<10>(a, sm, tid, cpw)) return;
    float sx = 0.f, sy = 0.f, sz = 0.f;
    #pragma unroll
    for (int m = 0; m < 10; ++m) {
      int j = (int)(__float_as_uint(a[m]) & 0x1FFFu);
      sx += p2[j]; sy += p2[N + j]; sz += p2[2 * N + j];
    }
    const float inv9 = 1.f / 9.f;
    P.cv2[b * NTOT + off + i] = make_float4((sx - 10.f * ax) * inv9,
                                            (sy - 10.f * ay) * inv9,
                                            (sz - 10.f * az) * inv9, 0.f);
  } else if (pass == 1) {
    float ax = p1[i], ay = p1[N + i], az = p1[2 * N + i];
    float a[10], bb[10];
    #pragma unroll
    for (int m = 0; m < 10; ++m) { a[m] = 3.0e38f; bb[m] = 3.0e38f; }
    scan_g<10>(p1, p1 + N, p1 + 2 * N, lo, ax, ay, az, a, bb);
    merge_pair<10>(a, bb);
    if (!merge_group<10>(a, sm, tid, cpw)) return;
    float fix = fl[i], fiy = fl[N + i], fiz = fl[2 * N + i];
    float wix = ax + fix, wiy = ay + fiy, wiz = az + fiz;
    float sx = 0.f, sy = 0.f, sz = 0.f, smooth = 0.f;
    float dmax = -1.f, worst = 0.f;
    #pragma unroll
    for (int m = 0; m < 10; ++m) {
      int j = (int)(__float_as_uint(a[m]) & 0x1FFFu);
      float px = p1[j], py = p1[N + j], pz = p1[2 * N + j];
      float flx = fl[j], fly = fl[N + j], flz = fl[2 * N + j];
      sx += px + flx; sy += py + fly; sz += pz + flz;
      float ddx = px - ax, ddy = py - ay, ddz = pz - az;
      float d = fmaf(ddx, ddx, fmaf(ddy, ddy, ddz * ddz));  // exact
      float gx = flx - fix, gy = fly - fiy, gz = flz - fiz;
      float term = sqrtf(fmaf(gx, gx, fmaf(gy, gy, gz * gz)));
      smooth += term;
      if (d > dmax) { dmax = d; worst = term; }  // drop farthest (k9)
    }
    smooth -= worst;
    const float inv9 = 1.f / 9.f;
    P.cvw[b * NTOT + off + i] = make_float4((sx - 10.f * wix) * inv9,
                                            (sy - 10.f * wiy) * inv9,
                                            (sz - 10.f * wiz) * inv9, 0.f);
    float ssum = wave_sum(smooth * (1.f / 8.f));
    if (q == 0) atomicAdd(P.out, alpha * 0.5f * ssum);
  } else if (pass == 2) {
    float ax = p1[i] + fl[i], ay = p1[N + i] + fl[N + i],
          az = p1[2 * N + i] + fl[2 * N + i];
    float a[5], bb[5];
    #pragma unroll
    for (int m = 0; m < 5; ++m) { a[m] = 3.0e38f; bb[m] = 3.0e38f; }
    scan_g<5>(p2, p2 + N, p2 + 2 * N, lo, ax, ay, az, a, bb);
    merge_pair<5>(a, bb);
    if (!merge_group<5>(a, sm, tid, cpw)) return;
    #pragma unroll
    for (int m = 0; m < 5; ++m)
      P.ckeys[(b * NTOT + off + i) * 5 + m] = a[m];
  } else {
    float ax = p2[i], ay = p2[N + i], az = p2[2 * N + i];
    float a = 3.0e38f, bb = 3.0e38f;
    scan_min(p1, p1 + N, p1 + 2 * N, fl, fl + N, fl + 2 * N,
             lo, ax, ay, az, a, bb, tiles[wv], q);
    float kd1[1];
    kd1[0] = fminf(a, bb);
    if (!merge_group<1>(kd1, sm, tid, cpw)) return;
    float msum = wave_sum(kd1[0]);
    if (q == 0) atomicAdd(P.out, alpha * 0.5f * msum);
  }
}

// Tail: pass-C epilogue. One thread per query: top-5 exact distances,
// inverse-distance cv2 interpolation, curvature + chamfer(dist1) atomic.
__global__ __launch_bounds__(256) void k_tail(Params P) {
  int g = blockIdx.x * 256 + threadIdx.x;   // [0, 30720)
  int b = (g >= NTOT) ? 1 : 0;
  int t = g - b * NTOT;
  int s = (t < 8192) ? 0 : (t < 12288) ? 1 : (t < 14336) ? 2 : 3;
  int off = 16384 - (16384 >> s);
  int N = 8192 >> s;
  int i = t - off;
  float alpha = 0.02f * (float)(1 << s);
  const float* __restrict__ p1 = P.pc1[s] + b * 3 * N;
  const float* __restrict__ fl = P.fl[s] + b * 3 * N;
  const float* __restrict__ p2 = P.pc2[s] + b * 3 * N;
  float ax = p1[i] + fl[i], ay = p1[N + i] + fl[N + i],
        az = p1[2 * N + i] + fl[2 * N + i];
  float dist1 = 3.0e38f, wsum = 0.f, ix = 0.f, iy = 0.f, iz = 0.f;
  #pragma unroll
  for (int m = 0; m < 5; ++m) {
    float key = P.ckeys[(b * NTOT + t) * 5 + m];
    int j = (int)(__float_as_uint(key) & 0x1FFFu);
    float px = p2[j], py = p2[N + j], pz = p2[2 * N + j];
    float ddx = px - ax, ddy = py - ay, ddz = pz - az;
    float d = fmaf(ddx, ddx, fmaf(ddy, ddy, ddz * ddz));  // exact
    dist1 = fminf(dist1, d);
    float w = 1.f / (d + 1e-8f);
    wsum += w;
    float4 cv = P.cv2[b * NTOT + off + j];
    ix += w * cv.x; iy += w * cv.y; iz += w * cv.z;
  }
  float inv = 1.f / wsum;
  ix *= inv; iy *= inv; iz *= inv;
  float4 cw = P.cvw[b * NTOT + t];
  float ex = ix - cw.x, ey = iy - cw.y, ez = iz - cw.z;
  float curv = fmaf(ex, ex, fmaf(ey, ey, ez * ez));
  float v = alpha * (dist1 + 0.3f * curv);   // per-lane alpha (boundaries)
  float csum = wave_sum(v);
  if ((threadIdx.x & 63) == 0) atomicAdd(P.out, 0.5f * csum);
}

extern "C" void kernel_launch(void* const* d_in, const int* in_sizes, int n_in,
                              void* d_out, int out_size, void* d_ws,
                              size_t ws_size, hipStream_t stream) {
  Params P;
  for (int s = 0; s < 4; ++s) {
    P.pc1[s] = (const float*)d_in[s];
    P.pc2[s] = (const float*)d_in[4 + s];
    P.fl[s]  = (const float*)d_in[8 + s];
  }
  P.cv2 = (float4*)d_ws;
  P.cvw = P.cv2 + 2 * NTOT;
  P.ckeys = (float*)(P.cvw + 2 * NTOT);   // 2*NTOT*5 floats = 614 KB
  P.out = (float*)d_out;

  k_zero<<<dim3(1), dim3(1), 0, stream>>>(P.out);
  k_fused<<<dim3(4 * PB), dim3(BLOCK), 0, stream>>>(P);
  k_tail<<<dim3(120), dim3(256), 0, stream>>>(P);
}

// Round 12
// 725.768 us; speedup vs baseline: 1.0001x; 1.0001x over previous
//
#include <hip/hip_runtime.h>
#include <math.h>

// PointPWC multi-scale loss. B=2, scales N={8192,4096,2048,1024}.
// Inputs (B,3,N) fp32 channel-major: pc1_0..3, pc2_0..3, flow_0..3.
// Output: single fp32 scalar.
//
// R12: R11's design (candidates via wave-uniform global float4 loads --
// off the LDS pipe) with the spill fixed: R11's scan_g was not inlined,
// so the by-reference top-k arrays were demoted to scratch (FETCH 292MB /
// WRITE 968MB of spill traffic, 2x regression). All scan/merge helpers
// are now __forceinline__; live set ~40 VGPR < 64 cap of (512,8).

#define BLOCK 512
#define UNIT 1024    // candidates per wave-unit
#define NTOT 15360   // 8192+4096+2048+1024
#define MASKC 0xFFFFE000u
#define PB 340       // blocks per pass
#define STR 11       // merge-staging stride (odd -> 2-way alias only)

typedef unsigned int uint;

struct Params {
  const float* __restrict__ pc1[4];
  const float* __restrict__ pc2[4];
  const float* __restrict__ fl[4];
  float4* __restrict__ cv2;   // [B][NTOT]
  float4* __restrict__ cvw;   // [B][NTOT]
  float* __restrict__ ckeys;  // [B][NTOT][5] pass-C merged top-5 keys
  float* __restrict__ out;
};

// r in [0,340) -> scale s, batch b, 64-query-group base i0, cand lo.
__device__ __forceinline__ void decode(int r, int wv, int& s, int& b,
                                       int& i0, int& lo, int& N, int& cpw,
                                       int& off, float& alpha) {
  int rr;
  if (r < 256)      { s = 0; rr = r; }
  else if (r < 320) { s = 1; rr = r - 256; }
  else if (r < 336) { s = 2; rr = r - 320; }
  else              { s = 3; rr = r - 336; }
  N = 8192 >> s;
  cpw = 8 >> s;                       // candidate-ranges per qgroup
  int perb = 128 >> (2 * s);          // blocks per batch
  b = rr >> (7 - 2 * s);
  int chunk = rr & (perb - 1);
  int qg = (chunk << s) + (wv >> (3 - s));
  i0 = qg << 6;
  lo = (wv & (cpw - 1)) << 10;
  off = 16384 - (16384 >> s);         // {0, 8192, 12288, 14336}
  alpha = 0.02f * (float)(1 << s);
}

__device__ __forceinline__ float wave_sum(float v) {
  #pragma unroll
  for (int o = 32; o; o >>= 1) v += __shfl_down(v, o, 64);
  return v;
}

template <int K>
__device__ __forceinline__ void key_insert(float (&kd)[K], float kf) {
  #pragma unroll
  for (int m = K - 1; m >= 1; --m)
    kd[m] = __builtin_amdgcn_fmed3f(kf, kd[m - 1], kd[m]);
  kd[0] = fminf(kd[0], kf);
}

template <int K>
__device__ __forceinline__ void merge_pair(float (&a)[K],
                                           const float (&b)[K]) {
  #pragma unroll
  for (int m = 0; m < K; ++m) key_insert<K>(a, b[m]);
}

__device__ __forceinline__ float pack_key(float d, uint iw) {
  return __uint_as_float((__float_as_uint(d) & MASKC) | iw);
}

// Scan [lo, lo+UNIT): 1 query/thread, dual chains, candidates read as
// wave-uniform float4 global loads (no LDS; 3 loads / 4 candidates).
template <int K>
__device__ __forceinline__ void scan_g(const float* __restrict__ px,
                                       const float* __restrict__ py,
                                       const float* __restrict__ pz,
                                       int lo, float ax, float ay, float az,
                                       float (&a)[K], float (&b)[K]) {
  const float4* __restrict__ px4 = (const float4*)(px + lo);
  const float4* __restrict__ py4 = (const float4*)(py + lo);
  const float4* __restrict__ pz4 = (const float4*)(pz + lo);
  #pragma unroll 4
  for (int g = 0; g < UNIT / 4; ++g) {
    float4 xs = px4[g], ys = py4[g], zs = pz4[g];
    uint c = (uint)(lo + g * 4);
    float dx0 = ax - xs.x, dy0 = ay - ys.x, dz0 = az - zs.x;
    float d0 = fmaf(dx0, dx0, fmaf(dy0, dy0, dz0 * dz0));
    float dx1 = ax - xs.y, dy1 = ay - ys.y, dz1 = az - zs.y;
    float d1 = fmaf(dx1, dx1, fmaf(dy1, dy1, dz1 * dz1));
    float dx2 = ax - xs.z, dy2 = ay - ys.z, dz2 = az - zs.z;
    float d2 = fmaf(dx2, dx2, fmaf(dy2, dy2, dz2 * dz2));
    float dx3 = ax - xs.w, dy3 = ay - ys.w, dz3 = az - zs.w;
    float d3 = fmaf(dx3, dx3, fmaf(dy3, dy3, dz3 * dz3));
    key_insert<K>(a, pack_key(d0, c));
    key_insert<K>(b, pack_key(d2, c + 2));
    key_insert<K>(a, pack_key(d1, c + 1));
    key_insert<K>(b, pack_key(d3, c + 3));
  }
}

// Pass D scan: candidates are p1+fl, staged through this wave's private
// AoS float4 LDS tile (aligned ds_read_b128 broadcast). ~12% of blocks.
__device__ __forceinline__ void scan_min(const float* __restrict__ px,
                                         const float* __restrict__ py,
                                         const float* __restrict__ pz,
                                         const float* __restrict__ fx,
                                         const float* __restrict__ fy,
                                         const float* __restrict__ fz,
                                         int lo, float ax, float ay,
                                         float az, float& a, float& b,
                                         float4* tile, int lane) {
  int j = lo + lane;
  float x = px[j] + fx[j], y = py[j] + fy[j], z = pz[j] + fz[j];
  for (int c0 = lo; c0 < lo + UNIT; c0 += 64) {
    tile[lane] = make_float4(x, y, z, 0.f);
    asm volatile("s_waitcnt lgkmcnt(0)" ::: "memory");
    if (c0 + 64 < lo + UNIT) {
      int jn = j + 64;
      x = px[jn] + fx[jn]; y = py[jn] + fy[jn]; z = pz[jn] + fz[jn];
    }
    #pragma unroll 8
    for (int t = 0; t < 64; t += 2) {
      float4 cA = tile[t];
      float4 cB = tile[t + 1];
      float dxa = ax - cA.x, dya = ay - cA.y, dza = az - cA.z;
      float dA = fmaf(dxa, dxa, fmaf(dya, dya, dza * dza));
      float dxb = ax - cB.x, dyb = ay - cB.y, dzb = az - cB.z;
      float dB = fmaf(dxb, dxb, fmaf(dyb, dyb, dzb * dzb));
      a = fminf(a, dA);
      b = fminf(b, dB);
    }
    j += 64;
  }
}

// Stage per-thread list; group leader (wave with range 0) merges its
// qgroup's cpw lists. Returns true for leader threads.
template <int K>
__device__ __forceinline__ bool merge_group(float (&a)[K], float* sm,
                                            int tid, int cpw) {
  int q = tid & 63, wv = tid >> 6;
  #pragma unroll
  for (int m = 0; m < K; ++m) sm[(wv * 64 + q) * STR + m] = a[m];
  __syncthreads();
  if (wv & (cpw - 1)) return false;
  for (int w = wv + 1; w < wv + cpw; ++w)
    #pragma unroll
    for (int m = 0; m < K; ++m)
      key_insert<K>(a, sm[(w * 64 + q) * STR + m]);
  return true;
}

__global__ __launch_bounds__(1) void k_zero(float* out) { out[0] = 0.f; }

// pass 0 (A): self-KNN p2 k=10 -> cv2
// pass 1 (B): self-KNN p1 k=10 -> cvw + smoothness
// pass 2 (C): warp->p2 top-5 scan -> merged keys to ws (epilogue: k_tail)
// pass 3 (D): p2 -> warp min (dist2)
__global__ __launch_bounds__(BLOCK, 8) void k_fused(Params P) {
  __shared__ float4 tiles[8][64];        // 8 KB (pass D only)
  __shared__ float sm[8 * 64 * STR];     // 22.5 KB
  int tid = threadIdx.x, q = tid & 63, wv = tid >> 6;
  int pass = blockIdx.x & 3, r = blockIdx.x >> 2;
  int s, b, i0, lo, N, cpw, off; float alpha;
  decode(r, wv, s, b, i0, lo, N, cpw, off, alpha);
  int i = i0 + q;

  const float* __restrict__ p1 = P.pc1[s] + b * 3 * N;
  const float* __restrict__ fl = P.fl[s] + b * 3 * N;
  const float* __restrict__ p2 = P.pc2[s] + b * 3 * N;

  if (pass == 0) {
    float ax = p2[i], ay = p2[N + i], az = p2[2 * N + i];
    float a[10], bb[10];
    #pragma unroll
    for (int m = 0; m < 10; ++m) { a[m] = 3.0e38f; bb[m] = 3.0e38f; }
    scan_g<10>(p2, p2 + N, p2 + 2 * N, lo, ax, ay, az, a, bb);
    merge_pair<10>(a, bb);
    if (!merge_group<10>(a, sm, tid, cpw)) return;
    float sx = 0.f, sy = 0.f, sz = 0.f;
    #pragma unroll
    for (int m = 0; m < 10; ++m) {
      int j = (int)(__float_as_uint(a[m]) & 0x1FFFu);
      sx += p2[j]; sy += p2[N + j]; sz += p2[2 * N + j];
    }
    const float inv9 = 1.f / 9.f;
    P.cv2[b * NTOT + off + i] = make_float4((sx - 10.f * ax) * inv9,
                                            (sy - 10.f * ay) * inv9,
                                            (sz - 10.f * az) * inv9, 0.f);
  } else if (pass == 1) {
    float ax = p1[i], ay = p1[N + i], az = p1[2 * N + i];
    float a[10], bb[10];
    #pragma unroll
    for (int m = 0; m < 10; ++m) { a[m] = 3.0e38f; bb[m] = 3.0e38f; }
    scan_g<10>(p1, p1 + N, p1 + 2 * N, lo, ax, ay, az, a, bb);
    merge_pair<10>(a, bb);
    if (!merge_group<10>(a, sm, tid, cpw)) return;
    float fix = fl[i], fiy = fl[N + i], fiz = fl[2 * N + i];
    float wix = ax + fix, wiy = ay + fiy, wiz = az + fiz;
    float sx = 0.f, sy = 0.f, sz = 0.f, smooth = 0.f;
    float dmax = -1.f, worst = 0.f;
    #pragma unroll
    for (int m = 0; m < 10; ++m) {
      int j = (int)(__float_as_uint(a[m]) & 0x1FFFu);
      float px = p1[j], py = p1[N + j], pz = p1[2 * N + j];
      float flx = fl[j], fly = fl[N + j], flz = fl[2 * N + j];
      sx += px + flx; sy += py + fly; sz += pz + flz;
      float ddx = px - ax, ddy = py - ay, ddz = pz - az;
      float d = fmaf(ddx, ddx, fmaf(ddy, ddy, ddz * ddz));  // exact
      float gx = flx - fix, gy = fly - fiy, gz = flz - fiz;
      float term = sqrtf(fmaf(gx, gx, fmaf(gy, gy, gz * gz)));
      smooth += term;
      if (d > dmax) { dmax = d; worst = term; }  // drop farthest (k9)
    }
    smooth -= worst;
    const float inv9 = 1.f / 9.f;
    P.cvw[b * NTOT + off + i] = make_float4((sx - 10.f * wix) * inv9,
                                            (sy - 10.f * wiy) * inv9,
                                            (sz - 10.f * wiz) * inv9, 0.f);
    float ssum = wave_sum(smooth * (1.f / 8.f));
    if (q == 0) atomicAdd(P.out, alpha * 0.5f * ssum);
  } else if (pass == 2) {
    float ax = p1[i] + fl[i], ay = p1[N + i] + fl[N + i],
          az = p1[2 * N + i] + fl[2 * N + i];
    float a[5], bb[5];
    #pragma unroll
    for (int m = 0; m < 5; ++m) { a[m] = 3.0e38f; bb[m] = 3.0e38f; }
    scan_g<5>(p2, p2 + N, p2 + 2 * N, lo, ax, ay, az, a, bb);
    merge_pair<5>(a, bb);
    if (!merge_group<5>(a, sm, tid, cpw)) return;
    #pragma unroll
    for (int m = 0; m < 5; ++m)
      P.ckeys[(b * NTOT + off + i) * 5 + m] = a[m];
  } else {
    float ax = p2[i], ay = p2[N + i], az = p2[2 * N + i];
    float a = 3.0e38f, bb = 3.0e38f;
    scan_min(p1, p1 + N, p1 + 2 * N, fl, fl + N, fl + 2 * N,
             lo, ax, ay, az, a, bb, tiles[wv], q);
    float kd1[1];
    kd1[0] = fminf(a, bb);
    if (!merge_group<1>(kd1, sm, tid, cpw)) return;
    float msum = wave_sum(kd1[0]);
    if (q == 0) atomicAdd(P.out, alpha * 0.5f * msum);
  }
}

// Tail: pass-C epilogue. One thread per query: top-5 exact distances,
// inverse-distance cv2 interpolation, curvature + chamfer(dist1) atomic.
__global__ __launch_bounds__(256) void k_tail(Params P) {
  int g = blockIdx.x * 256 + threadIdx.x;   // [0, 30720)
  int b = (g >= NTOT) ? 1 : 0;
  int t = g - b * NTOT;
  int s = (t < 8192) ? 0 : (t < 12288) ? 1 : (t < 14336) ? 2 : 3;
  int off = 16384 - (16384 >> s);
  int N = 8192 >> s;
  int i = t - off;
  float alpha = 0.02f * (float)(1 << s);
  const float* __restrict__ p1 = P.pc1[s] + b * 3 * N;
  const float* __restrict__ fl = P.fl[s] + b * 3 * N;
  const float* __restrict__ p2 = P.pc2[s] + b * 3 * N;
  float ax = p1[i] + fl[i], ay = p1[N + i] + fl[N + i],
        az = p1[2 * N + i] + fl[2 * N + i];
  float dist1 = 3.0e38f, wsum = 0.f, ix = 0.f, iy = 0.f, iz = 0.f;
  #pragma unroll
  for (int m = 0; m < 5; ++m) {
    float key = P.ckeys[(b * NTOT + t) * 5 + m];
    int j = (int)(__float_as_uint(key) & 0x1FFFu);
    float px = p2[j], py = p2[N + j], pz = p2[2 * N + j];
    float ddx = px - ax, ddy = py - ay, ddz = pz - az;
    float d = fmaf(ddx, ddx, fmaf(ddy, ddy, ddz * ddz));  // exact
    dist1 = fminf(dist1, d);
    float w = 1.f / (d + 1e-8f);
    wsum += w;
    float4 cv = P.cv2[b * NTOT + off + j];
    ix += w * cv.x; iy += w * cv.y; iz += w * cv.z;
  }
  float inv = 1.f / wsum;
  ix *= inv; iy *= inv; iz *= inv;
  float4 cw = P.cvw[b * NTOT + t];
  float ex = ix - cw.x, ey = iy - cw.y, ez = iz - cw.z;
  float curv = fmaf(ex, ex, fmaf(ey, ey, ez * ez));
  float v = alpha * (dist1 + 0.3f * curv);   // per-lane alpha (boundaries)
  float csum = wave_sum(v);
  if ((threadIdx.x & 63) == 0) atomicAdd(P.out, 0.5f * csum);
}

extern "C" void kernel_launch(void* const* d_in, const int* in_sizes, int n_in,
                              void* d_out, int out_size, void* d_ws,
                              size_t ws_size, hipStream_t stream) {
  Params P;
  for (int s = 0; s < 4; ++s) {
    P.pc1[s] = (const float*)d_in[s];
    P.pc2[s] = (const float*)d_in[4 + s];
    P.fl[s]  = (const float*)d_in[8 + s];
  }
  P.cv2 = (float4*)d_ws;
  P.cvw = P.cv2 + 2 * NTOT;
  P.ckeys = (float*)(P.cvw + 2 * NTOT);   // 2*NTOT*5 floats = 614 KB
  P.out = (float*)d_out;

  k_zero<<<dim3(1), dim3(1), 0, stream>>>(P.out);
  k_fused<<<dim3(4 * PB), dim3(BLOCK), 0, stream>>>(P);
  k_tail<<<dim3(120), dim3(256), 0, stream>>>(P);
}

// Round 13
// 425.576 us; speedup vs baseline: 1.7056x; 1.7054x over previous
//
#include <hip/hip_runtime.h>
#include <math.h>

// PointPWC multi-scale loss. B=2, scales N={8192,4096,2048,1024}.
// Inputs (B,3,N) fp32 channel-major: pc1_0..3, pc2_0..3, flow_0..3.
// Output: single fp32 scalar.
//
// R13: R12 (candidates via wave-uniform global float4 loads, off the LDS
// pipe) with the REAL spill cause fixed. R11/R12's 1.3GB scratch traffic
// was register pressure: unroll-4 held 48 load VGPRs in flight and
// launch_bounds(512,8) caps threads at 64 VGPRs -> kd arrays demoted to
// scratch. Fix: unroll 2 (~55 live regs) + launch_bounds(512,6) (~85 VGPR
// cap, 3 blocks/CU = 24 waves/CU, >= R8's achieved occupancy).
// LDS-pipe model (R5/R8/R10 fit): ds_read_b128 broadcast ~12 cyc of the
// shared per-CU pipe vs ~5 needed to feed 4 SIMDs -> 2.4x wall/issue.
// VMEM same-address broadcast = 1 coalesced L1 line, far below capacity.

#define BLOCK 512
#define UNIT 1024    // candidates per wave-unit
#define NTOT 15360   // 8192+4096+2048+1024
#define MASKC 0xFFFFE000u
#define PB 340       // blocks per pass
#define STR 11       // merge-staging stride (odd -> 2-way alias only)

typedef unsigned int uint;

struct Params {
  const float* __restrict__ pc1[4];
  const float* __restrict__ pc2[4];
  const float* __restrict__ fl[4];
  float4* __restrict__ cv2;   // [B][NTOT]
  float4* __restrict__ cvw;   // [B][NTOT]
  float* __restrict__ ckeys;  // [B][NTOT][5] pass-C merged top-5 keys
  float* __restrict__ out;
};

// r in [0,340) -> scale s, batch b, 64-query-group base i0, cand lo.
__device__ __forceinline__ void decode(int r, int wv, int& s, int& b,
                                       int& i0, int& lo, int& N, int& cpw,
                                       int& off, float& alpha) {
  int rr;
  if (r < 256)      { s = 0; rr = r; }
  else if (r < 320) { s = 1; rr = r - 256; }
  else if (r < 336) { s = 2; rr = r - 320; }
  else              { s = 3; rr = r - 336; }
  N = 8192 >> s;
  cpw = 8 >> s;                       // candidate-ranges per qgroup
  int perb = 128 >> (2 * s);          // blocks per batch
  b = rr >> (7 - 2 * s);
  int chunk = rr & (perb - 1);
  int qg = (chunk << s) + (wv >> (3 - s));
  i0 = qg << 6;
  lo = (wv & (cpw - 1)) << 10;
  off = 16384 - (16384 >> s);         // {0, 8192, 12288, 14336}
  alpha = 0.02f * (float)(1 << s);
}

__device__ __forceinline__ float wave_sum(float v) {
  #pragma unroll
  for (int o = 32; o; o >>= 1) v += __shfl_down(v, o, 64);
  return v;
}

template <int K>
__device__ __forceinline__ void key_insert(float (&kd)[K], float kf) {
  #pragma unroll
  for (int m = K - 1; m >= 1; --m)
    kd[m] = __builtin_amdgcn_fmed3f(kf, kd[m - 1], kd[m]);
  kd[0] = fminf(kd[0], kf);
}

template <int K>
__device__ __forceinline__ void merge_pair(float (&a)[K],
                                           const float (&b)[K]) {
  #pragma unroll
  for (int m = 0; m < K; ++m) key_insert<K>(a, b[m]);
}

__device__ __forceinline__ float pack_key(float d, uint iw) {
  return __uint_as_float((__float_as_uint(d) & MASKC) | iw);
}

// Scan [lo, lo+UNIT): 1 query/thread, dual chains, candidates read as
// wave-uniform float4 global loads (no LDS; 3 loads / 4 candidates).
// unroll 2: ~24 load regs in flight, bounded pressure.
template <int K>
__device__ __forceinline__ void scan_g(const float* __restrict__ px,
                                       const float* __restrict__ py,
                                       const float* __restrict__ pz,
                                       int lo, float ax, float ay, float az,
                                       float (&a)[K], float (&b)[K]) {
  const float4* __restrict__ px4 = (const float4*)(px + lo);
  const float4* __restrict__ py4 = (const float4*)(py + lo);
  const float4* __restrict__ pz4 = (const float4*)(pz + lo);
  #pragma unroll 2
  for (int g = 0; g < UNIT / 4; ++g) {
    float4 xs = px4[g], ys = py4[g], zs = pz4[g];
    uint c = (uint)(lo + g * 4);
    float dx0 = ax - xs.x, dy0 = ay - ys.x, dz0 = az - zs.x;
    float d0 = fmaf(dx0, dx0, fmaf(dy0, dy0, dz0 * dz0));
    float dx1 = ax - xs.y, dy1 = ay - ys.y, dz1 = az - zs.y;
    float d1 = fmaf(dx1, dx1, fmaf(dy1, dy1, dz1 * dz1));
    float dx2 = ax - xs.z, dy2 = ay - ys.z, dz2 = az - zs.z;
    float d2 = fmaf(dx2, dx2, fmaf(dy2, dy2, dz2 * dz2));
    float dx3 = ax - xs.w, dy3 = ay - ys.w, dz3 = az - zs.w;
    float d3 = fmaf(dx3, dx3, fmaf(dy3, dy3, dz3 * dz3));
    key_insert<K>(a, pack_key(d0, c));
    key_insert<K>(b, pack_key(d2, c + 2));
    key_insert<K>(a, pack_key(d1, c + 1));
    key_insert<K>(b, pack_key(d3, c + 3));
  }
}

// Pass D scan: candidates are p1+fl, staged through this wave's private
// AoS float4 LDS tile (aligned ds_read_b128 broadcast). ~25% of blocks,
// LDS pipe unsaturated at that share.
__device__ __forceinline__ void scan_min(const float* __restrict__ px,
                                         const float* __restrict__ py,
                                         const float* __restrict__ pz,
                                         const float* __restrict__ fx,
                                         const float* __restrict__ fy,
                                         const float* __restrict__ fz,
                                         int lo, float ax, float ay,
                                         float az, float& a, float& b,
                                         float4* tile, int lane) {
  int j = lo + lane;
  float x = px[j] + fx[j], y = py[j] + fy[j], z = pz[j] + fz[j];
  for (int c0 = lo; c0 < lo + UNIT; c0 += 64) {
    tile[lane] = make_float4(x, y, z, 0.f);
    asm volatile("s_waitcnt lgkmcnt(0)" ::: "memory");
    if (c0 + 64 < lo + UNIT) {
      int jn = j + 64;
      x = px[jn] + fx[jn]; y = py[jn] + fy[jn]; z = pz[jn] + fz[jn];
    }
    #pragma unroll 8
    for (int t = 0; t < 64; t += 2) {
      float4 cA = tile[t];
      float4 cB = tile[t + 1];
      float dxa = ax - cA.x, dya = ay - cA.y, dza = az - cA.z;
      float dA = fmaf(dxa, dxa, fmaf(dya, dya, dza * dza));
      float dxb = ax - cB.x, dyb = ay - cB.y, dzb = az - cB.z;
      float dB = fmaf(dxb, dxb, fmaf(dyb, dyb, dzb * dzb));
      a = fminf(a, dA);
      b = fminf(b, dB);
    }
    j += 64;
  }
}

// Stage per-thread list; group leader (wave with range 0) merges its
// qgroup's cpw lists. Returns true for leader threads.
template <int K>
__device__ __forceinline__ bool merge_group(float (&a)[K], float* sm,
                                            int tid, int cpw) {
  int q = tid & 63, wv = tid >> 6;
  #pragma unroll
  for (int m = 0; m < K; ++m) sm[(wv * 64 + q) * STR + m] = a[m];
  __syncthreads();
  if (wv & (cpw - 1)) return false;
  for (int w = wv + 1; w < wv + cpw; ++w)
    #pragma unroll
    for (int m = 0; m < K; ++m)
      key_insert<K>(a, sm[(w * 64 + q) * STR + m]);
  return true;
}

__global__ __launch_bounds__(1) void k_zero(float* out) { out[0] = 0.f; }

// pass 0 (A): self-KNN p2 k=10 -> cv2
// pass 1 (B): self-KNN p1 k=10 -> cvw + smoothness
// pass 2 (C): warp->p2 top-5 scan -> merged keys to ws (epilogue: k_tail)
// pass 3 (D): p2 -> warp min (dist2)
__global__ __launch_bounds__(BLOCK, 6) void k_fused(Params P) {
  __shared__ float4 tiles[8][64];        // 8 KB (pass D only)
  __shared__ float sm[8 * 64 * STR];     // 22.5 KB
  int tid = threadIdx.x, q = tid & 63, wv = tid >> 6;
  int pass = blockIdx.x & 3, r = blockIdx.x >> 2;
  int s, b, i0, lo, N, cpw, off; float alpha;
  decode(r, wv, s, b, i0, lo, N, cpw, off, alpha);
  int i = i0 + q;

  const float* __restrict__ p1 = P.pc1[s] + b * 3 * N;
  const float* __restrict__ fl = P.fl[s] + b * 3 * N;
  const float* __restrict__ p2 = P.pc2[s] + b * 3 * N;

  if (pass == 0) {
    float ax = p2[i], ay = p2[N + i], az = p2[2 * N + i];
    float a[10], bb[10];
    #pragma unroll
    for (int m = 0; m < 10; ++m) { a[m] = 3.0e38f; bb[m] = 3.0e38f; }
    scan_g<10>(p2, p2 + N, p2 + 2 * N, lo, ax, ay, az, a, bb);
    merge_pair<10>(a, bb);
    if (!merge_group<10>(a, sm, tid, cpw)) return;
    float sx = 0.f, sy = 0.f, sz = 0.f;
    #pragma unroll
    for (int m = 0; m < 10; ++m) {
      int j = (int)(__float_as_uint(a[m]) & 0x1FFFu);
      sx += p2[j]; sy += p2[N + j]; sz += p2[2 * N + j];
    }
    const float inv9 = 1.f / 9.f;
    P.cv2[b * NTOT + off + i] = make_float4((sx - 10.f * ax) * inv9,
                                            (sy - 10.f * ay) * inv9,
                                            (sz - 10.f * az) * inv9, 0.f);
  } else if (pass == 1) {
    float ax = p1[i], ay = p1[N + i], az = p1[2 * N + i];
    float a[10], bb[10];
    #pragma unroll
    for (int m = 0; m < 10; ++m) { a[m] = 3.0e38f; bb[m] = 3.0e38f; }
    scan_g<10>(p1, p1 + N, p1 + 2 * N, lo, ax, ay, az, a, bb);
    merge_pair<10>(a, bb);
    if (!merge_group<10>(a, sm, tid, cpw)) return;
    float fix = fl[i], fiy = fl[N + i], fiz = fl[2 * N + i];
    float wix = ax + fix, wiy = ay + fiy, wiz = az + fiz;
    float sx = 0.f, sy = 0.f, sz = 0.f, smooth = 0.f;
    float dmax = -1.f, worst = 0.f;
    #pragma unroll
    for (int m = 0; m < 10; ++m) {
      int j = (int)(__float_as_uint(a[m]) & 0x1FFFu);
      float px = p1[j], py = p1[N + j], pz = p1[2 * N + j];
      float flx = fl[j], fly = fl[N + j], flz = fl[2 * N + j];
      sx += px + flx; sy += py + fly; sz += pz + flz;
      float ddx = px - ax, ddy = py - ay, ddz = pz - az;
      float d = fmaf(ddx, ddx, fmaf(ddy, ddy, ddz * ddz));  // exact
      float gx = flx - fix, gy = fly - fiy, gz = flz - fiz;
      float term = sqrtf(fmaf(gx, gx, fmaf(gy, gy, gz * gz)));
      smooth += term;
      if (d > dmax) { dmax = d; worst = term; }  // drop farthest (k9)
    }
    smooth -= worst;
    const float inv9 = 1.f / 9.f;
    P.cvw[b * NTOT + off + i] = make_float4((sx - 10.f * wix) * inv9,
                                            (sy - 10.f * wiy) * inv9,
                                            (sz - 10.f * wiz) * inv9, 0.f);
    float ssum = wave_sum(smooth * (1.f / 8.f));
    if (q == 0) atomicAdd(P.out, alpha * 0.5f * ssum);
  } else if (pass == 2) {
    float ax = p1[i] + fl[i], ay = p1[N + i] + fl[N + i],
          az = p1[2 * N + i] + fl[2 * N + i];
    float a[5], bb[5];
    #pragma unroll
    for (int m = 0; m < 5; ++m) { a[m] = 3.0e38f; bb[m] = 3.0e38f; }
    scan_g<5>(p2, p2 + N, p2 + 2 * N, lo, ax, ay, az, a, bb);
    merge_pair<5>(a, bb);
    if (!merge_group<5>(a, sm, tid, cpw)) return;
    #pragma unroll
    for (int m = 0; m < 5; ++m)
      P.ckeys[(b * NTOT + off + i) * 5 + m] = a[m];
  } else {
    float ax = p2[i], ay = p2[N + i], az = p2[2 * N + i];
    float a = 3.0e38f, bb = 3.0e38f;
    scan_min(p1, p1 + N, p1 + 2 * N, fl, fl + N, fl + 2 * N,
             lo, ax, ay, az, a, bb, tiles[wv], q);
    float kd1[1];
    kd1[0] = fminf(a, bb);
    if (!merge_group<1>(kd1, sm, tid, cpw)) return;
    float msum = wave_sum(kd1[0]);
    if (q == 0) atomicAdd(P.out, alpha * 0.5f * msum);
  }
}

// Tail: pass-C epilogue. One thread per query: top-5 exact distances,
// inverse-distance cv2 interpolation, curvature + chamfer(dist1) atomic.
__global__ __launch_bounds__(256) void k_tail(Params P) {
  int g = blockIdx.x * 256 + threadIdx.x;   // [0, 30720)
  int b = (g >= NTOT) ? 1 : 0;
  int t = g - b * NTOT;
  int s = (t < 8192) ? 0 : (t < 12288) ? 1 : (t < 14336) ? 2 : 3;
  int off = 16384 - (16384 >> s);
  int N = 8192 >> s;
  int i = t - off;
  float alpha = 0.02f * (float)(1 << s);
  const float* __restrict__ p1 = P.pc1[s] + b * 3 * N;
  const float* __restrict__ fl = P.fl[s] + b * 3 * N;
  const float* __restrict__ p2 = P.pc2[s] + b * 3 * N;
  float ax = p1[i] + fl[i], ay = p1[N + i] + fl[N + i],
        az = p1[2 * N + i] + fl[2 * N + i];
  float dist1 = 3.0e38f, wsum = 0.f, ix = 0.f, iy = 0.f, iz = 0.f;
  #pragma unroll
  for (int m = 0; m < 5; ++m) {
    float key = P.ckeys[(b * NTOT + t) * 5 + m];
    int j = (int)(__float_as_uint(key) & 0x1FFFu);
    float px = p2[j], py = p2[N + j], pz = p2[2 * N + j];
    float ddx = px - ax, ddy = py - ay, ddz = pz - az;
    float d = fmaf(ddx, ddx, fmaf(ddy, ddy, ddz * ddz));  // exact
    dist1 = fminf(dist1, d);
    float w = 1.f / (d + 1e-8f);
    wsum += w;
    float4 cv = P.cv2[b * NTOT + off + j];
    ix += w * cv.x; iy += w * cv.y; iz += w * cv.z;
  }
  float inv = 1.f / wsum;
  ix *= inv; iy *= inv; iz *= inv;
  float4 cw = P.cvw[b * NTOT + t];
  float ex = ix - cw.x, ey = iy - cw.y, ez = iz - cw.z;
  float curv = fmaf(ex, ex, fmaf(ey, ey, ez * ez));
  float v = alpha * (dist1 + 0.3f * curv);   // per-lane alpha (boundaries)
  float csum = wave_sum(v);
  if ((threadIdx.x & 63) == 0) atomicAdd(P.out, 0.5f * csum);
}

extern "C" void kernel_launch(void* const* d_in, const int* in_sizes, int n_in,
                              void* d_out, int out_size, void* d_ws,
                              size_t ws_size, hipStream_t stream) {
  Params P;
  for (int s = 0; s < 4; ++s) {
    P.pc1[s] = (const float*)d_in[s];
    P.pc2[s] = (const float*)d_in[4 + s];
    P.fl[s]  = (const float*)d_in[8 + s];
  }
  P.cv2 = (float4*)d_ws;
  P.cvw = P.cv2 + 2 * NTOT;
  P.ckeys = (float*)(P.cvw + 2 * NTOT);   // 2*NTOT*5 floats = 614 KB
  P.out = (float*)d_out;

  k_zero<<<dim3(1), dim3(1), 0, stream>>>(P.out);
  k_fused<<<dim3(4 * PB), dim3(BLOCK), 0, stream>>>(P);
  k_tail<<<dim3(120), dim3(256), 0, stream>>>(P);
}